// Round 1
// baseline (16836.862 us; speedup 1.0000x reference)
//
#include <hip/hip_runtime.h>

#define DIM 128
#define TM  32

// Y = X @ W (+ b0+b1+b2 if b0 != nullptr).  X:[N,128] W:[128,128] row-major.
// Block: 256 threads, 32-row tile. thread -> (col = t&127, rowhalf = t>>7).
// LDS x-tile padded to 132 floats/row: float4-aligned, reads are same-address
// broadcasts across the wave (lanes differ only in col) -> conflict-free.
__global__ __launch_bounds__(256) void gemm_k(
    const float* __restrict__ X, const float* __restrict__ W,
    const float* __restrict__ b0, const float* __restrict__ b1,
    const float* __restrict__ b2, float* __restrict__ Y, int N)
{
    __shared__ __align__(16) float xs[TM][DIM + 4];
    const int t  = threadIdx.x;
    const int m0 = blockIdx.x * TM;

    // stage X tile, float4-coalesced (32 float4 per row, 1024 total / 256 thr)
    for (int idx = t; idx < TM * (DIM / 4); idx += 256) {
        const int r  = idx >> 5;
        const int c4 = (idx & 31) << 2;
        float4 v = make_float4(0.f, 0.f, 0.f, 0.f);
        if (m0 + r < N) v = *(const float4*)(X + (size_t)(m0 + r) * DIM + c4);
        *(float4*)&xs[r][c4] = v;
    }
    __syncthreads();

    const int c  = t & 127;
    const int r0 = (t >> 7) << 4;   // 0 or 16

    float acc[16];
#pragma unroll
    for (int i = 0; i < 16; ++i) acc[i] = 0.f;

#pragma unroll 4
    for (int k = 0; k < DIM; k += 4) {
        const float w0 = W[(k + 0) * DIM + c];
        const float w1 = W[(k + 1) * DIM + c];
        const float w2 = W[(k + 2) * DIM + c];
        const float w3 = W[(k + 3) * DIM + c];
#pragma unroll
        for (int i = 0; i < 16; ++i) {
            const float4 xv = *(const float4*)&xs[r0 + i][k];
            acc[i] = fmaf(xv.x, w0, acc[i]);
            acc[i] = fmaf(xv.y, w1, acc[i]);
            acc[i] = fmaf(xv.z, w2, acc[i]);
            acc[i] = fmaf(xv.w, w3, acc[i]);
        }
    }

    float bias = 0.f;
    if (b0) bias = b0[c] + b1[c] + b2[c];

#pragma unroll
    for (int i = 0; i < 16; ++i) {
        const int m = m0 + r0 + i;
        if (m < N) Y[(size_t)m * DIM + c] = acc[i] + bias;
    }
}

// Y[dst[e]] += ea[e] * H[src[e]]  — one thread per (edge, float4 chunk).
__global__ __launch_bounds__(256) void scatter_k(
    const float* __restrict__ H, const int* __restrict__ src,
    const int* __restrict__ dst, const float* __restrict__ ea,
    float* __restrict__ Y, long long total)
{
    const long long i = (long long)blockIdx.x * 256 + threadIdx.x;
    if (i >= total) return;
    const int e = (int)(i >> 5);
    const int f = ((int)(i & 31)) << 2;
    const int s = src[e];
    const int d = dst[e];
    const float w = ea[e];
    const float4 hv = *(const float4*)(H + (size_t)s * DIM + f);
    float* yp = Y + (size_t)d * DIM + f;
    atomicAdd(yp + 0, w * hv.x);
    atomicAdd(yp + 1, w * hv.y);
    atomicAdd(yp + 2, w * hv.z);
    atomicAdd(yp + 3, w * hv.w);
}

extern "C" void kernel_launch(void* const* d_in, const int* in_sizes, int n_in,
                              void* d_out, int out_size, void* d_ws, size_t ws_size,
                              hipStream_t stream)
{
    const float* x   = (const float*)d_in[0];
    const int*   ei  = (const int*)d_in[1];
    const float* ea  = (const float*)d_in[2];
    const int*   ei2 = (const int*)d_in[3];
    const float* ea2 = (const float*)d_in[4];

    const int N  = in_sizes[0] / DIM;
    const int E  = in_sizes[2];
    const int E2 = in_sizes[4];

    float* OUT = (float*)d_out;
    float* B   = (float*)d_ws;                 // node buffer (block-1 output)
    float* H   = B + (size_t)N * DIM;          // message buffer (reused)

    const int gGemm = (N + TM - 1) / TM;
    const long long tot1 = (long long)E  * (DIM / 4);
    const long long tot2 = (long long)E2 * (DIM / 4);
    const int gS1 = (int)((tot1 + 255) / 256);
    const int gS2 = (int)((tot2 + 255) / 256);

    const float* cur = x;
    for (int b = 0; b < 3; ++b) {
        const float* lnw = (const float*)d_in[5 + 6 * b + 0];
        const float* lnb = (const float*)d_in[5 + 6 * b + 1];
        const float* c1w = (const float*)d_in[5 + 6 * b + 2];
        const float* c1b = (const float*)d_in[5 + 6 * b + 3];
        const float* c2w = (const float*)d_in[5 + 6 * b + 4];
        const float* c2b = (const float*)d_in[5 + 6 * b + 5];

        float* y = (b == 1) ? B : OUT;   // b0 -> OUT, b1 -> ws, b2 -> OUT

        // out_init = x@lnw + (ln_b + c1_b + c2_b)
        gemm_k<<<gGemm, 256, 0, stream>>>(cur, lnw, lnb, c1b, c2b, y, N);
        // branch 1
        gemm_k<<<gGemm, 256, 0, stream>>>(cur, c1w, nullptr, nullptr, nullptr, H, N);
        scatter_k<<<gS1, 256, 0, stream>>>(H, ei, ei + E, ea, y, tot1);
        // branch 2
        gemm_k<<<gGemm, 256, 0, stream>>>(cur, c2w, nullptr, nullptr, nullptr, H, N);
        scatter_k<<<gS2, 256, 0, stream>>>(H, ei2, ei2 + E2, ea2, y, tot2);

        cur = y;
    }
}

// Round 2
// 1922.939 us; speedup vs baseline: 8.7558x; 8.7558x over previous
//
#include <hip/hip_runtime.h>

#define DIM 128
#define TM  32

// ---------------- GEMM: Y = X @ W (+ b0+b1+b2 if b0 != nullptr) --------------
__global__ __launch_bounds__(256) void gemm_k(
    const float* __restrict__ X, const float* __restrict__ W,
    const float* __restrict__ b0, const float* __restrict__ b1,
    const float* __restrict__ b2, float* __restrict__ Y, int N)
{
    __shared__ __align__(16) float xs[TM][DIM + 4];
    const int t  = threadIdx.x;
    const int m0 = blockIdx.x * TM;

    for (int idx = t; idx < TM * (DIM / 4); idx += 256) {
        const int r  = idx >> 5;
        const int c4 = (idx & 31) << 2;
        float4 v = make_float4(0.f, 0.f, 0.f, 0.f);
        if (m0 + r < N) v = *(const float4*)(X + (size_t)(m0 + r) * DIM + c4);
        *(float4*)&xs[r][c4] = v;
    }
    __syncthreads();

    const int c  = t & 127;
    const int r0 = (t >> 7) << 4;

    float acc[16];
#pragma unroll
    for (int i = 0; i < 16; ++i) acc[i] = 0.f;

#pragma unroll 4
    for (int k = 0; k < DIM; k += 4) {
        const float w0 = W[(k + 0) * DIM + c];
        const float w1 = W[(k + 1) * DIM + c];
        const float w2 = W[(k + 2) * DIM + c];
        const float w3 = W[(k + 3) * DIM + c];
#pragma unroll
        for (int i = 0; i < 16; ++i) {
            const float4 xv = *(const float4*)&xs[r0 + i][k];
            acc[i] = fmaf(xv.x, w0, acc[i]);
            acc[i] = fmaf(xv.y, w1, acc[i]);
            acc[i] = fmaf(xv.z, w2, acc[i]);
            acc[i] = fmaf(xv.w, w3, acc[i]);
        }
    }

    float bias = 0.f;
    if (b0) bias = b0[c] + b1[c] + b2[c];

#pragma unroll
    for (int i = 0; i < 16; ++i) {
        const int m = m0 + r0 + i;
        if (m < N) Y[(size_t)m * DIM + c] = acc[i] + bias;
    }
}

// ---------------- CSR build ----------------
__global__ __launch_bounds__(256) void hist_k(
    const int* __restrict__ dst, int* __restrict__ cnt, int E)
{
    const int e = blockIdx.x * 256 + threadIdx.x;
    if (e < E) atomicAdd(&cnt[dst[e]], 1);
}

#define SCAN_B 1024
// exclusive scan, 1024 elems / block; block totals -> bsums
__global__ __launch_bounds__(256) void scan1_k(
    int* __restrict__ data, int* __restrict__ bsums, int n)
{
    __shared__ int sh[256];
    const int t = threadIdx.x;
    const int base = blockIdx.x * SCAN_B + t * 4;
    int v[4]; int s = 0;
#pragma unroll
    for (int i = 0; i < 4; ++i) {
        v[i] = (base + i < n) ? data[base + i] : 0;
        s += v[i];
    }
    sh[t] = s;
    __syncthreads();
    for (int off = 1; off < 256; off <<= 1) {
        int x = (t >= off) ? sh[t - off] : 0;
        __syncthreads();
        sh[t] += x;
        __syncthreads();
    }
    int run = (t == 0) ? 0 : sh[t - 1];
#pragma unroll
    for (int i = 0; i < 4; ++i) {
        if (base + i < n) data[base + i] = run;
        run += v[i];
    }
    if (t == 255) bsums[blockIdx.x] = sh[255];
}

// single-block exclusive scan of nb (<=256) block sums, in place
__global__ __launch_bounds__(256) void scan2_k(int* __restrict__ bsums, int nb)
{
    __shared__ int sh[256];
    const int t = threadIdx.x;
    sh[t] = (t < nb) ? bsums[t] : 0;
    __syncthreads();
    for (int off = 1; off < 256; off <<= 1) {
        int x = (t >= off) ? sh[t - off] : 0;
        __syncthreads();
        sh[t] += x;
        __syncthreads();
    }
    if (t < nb) bsums[t] = (t == 0) ? 0 : sh[t - 1];
}

__global__ __launch_bounds__(256) void scan3_k(
    int* __restrict__ data, const int* __restrict__ bsums, int n)
{
    const int i = blockIdx.x * 256 + threadIdx.x;
    if (i < n) data[i] += bsums[i / SCAN_B];
}

// bucket-scatter: srcs/wss sorted by dst. Mutates off -> inclusive prefix.
__global__ __launch_bounds__(256) void build_k(
    const int* __restrict__ src, const int* __restrict__ dst,
    const float* __restrict__ ea, int* __restrict__ off,
    int* __restrict__ srcs, float* __restrict__ wss, int E)
{
    const int e = blockIdx.x * 256 + threadIdx.x;
    if (e >= E) return;
    const int d = dst[e];
    const int pos = atomicAdd(&off[d], 1);
    srcs[pos] = src[e];
    wss[pos]  = ea[e];
}

// ---------------- gather: Y[d] += sum_j w[j] * H[srcs[j]] ----------------
// off is post-build inclusive prefix: start(d) = d ? off[d-1] : 0, end = off[d].
// 32 lanes (float4) per node, 8 nodes per 256-thread block. No atomics.
__global__ __launch_bounds__(256) void gather_k(
    const float* __restrict__ H, const int* __restrict__ srcs,
    const float* __restrict__ wss, const int* __restrict__ off,
    float* __restrict__ Y, int N)
{
    const int node = blockIdx.x * 8 + (threadIdx.x >> 5);
    if (node >= N) return;
    const int lane = threadIdx.x & 31;
    const int start = node ? off[node - 1] : 0;
    const int end   = off[node];

    float4 acc = make_float4(0.f, 0.f, 0.f, 0.f);
    for (int j = start; j < end; ++j) {
        const int   s = srcs[j];
        const float w = wss[j];
        const float4 h = *(const float4*)(H + (size_t)s * DIM + lane * 4);
        acc.x = fmaf(w, h.x, acc.x);
        acc.y = fmaf(w, h.y, acc.y);
        acc.z = fmaf(w, h.z, acc.z);
        acc.w = fmaf(w, h.w, acc.w);
    }

    float4* yp = (float4*)(Y + (size_t)node * DIM + lane * 4);
    float4 y = *yp;
    y.x += acc.x; y.y += acc.y; y.z += acc.z; y.w += acc.w;
    *yp = y;
}

extern "C" void kernel_launch(void* const* d_in, const int* in_sizes, int n_in,
                              void* d_out, int out_size, void* d_ws, size_t ws_size,
                              hipStream_t stream)
{
    const float* x   = (const float*)d_in[0];
    const int*   ei  = (const int*)d_in[1];
    const float* ea  = (const float*)d_in[2];
    const int*   ei2 = (const int*)d_in[3];
    const float* ea2 = (const float*)d_in[4];

    const int N  = in_sizes[0] / DIM;
    const int E  = in_sizes[2];
    const int E2 = in_sizes[4];

    float* OUT = (float*)d_out;

    // ---- workspace layout ----
    float* B    = (float*)d_ws;                 // N*DIM
    float* H    = B + (size_t)N * DIM;          // N*DIM
    int*   rp1  = (int*)(H + (size_t)N * DIM);  // N
    int*   rp2  = rp1 + N;                      // N
    int*   bsum = rp2 + N;                      // 256
    int*   srcs1 = bsum + 256;                  // E
    float* w1    = (float*)(srcs1 + E);         // E
    int*   srcs2 = (int*)(w1 + E);              // E2
    float* w2    = (float*)(srcs2 + E2);        // E2

    const int gE1 = (E + 255) / 256;
    const int gE2 = (E2 + 255) / 256;
    const int nb  = (N + SCAN_B - 1) / SCAN_B;  // <=256 required (N<=262144)
    const int gN256 = (N + 255) / 256;

    // ---- build CSR for both adjacencies (reused by all 3 blocks) ----
    hipMemsetAsync(rp1, 0, 2 * (size_t)N * sizeof(int), stream);
    hist_k<<<gE1, 256, 0, stream>>>(ei + E,  rp1, E);
    hist_k<<<gE2, 256, 0, stream>>>(ei2 + E2, rp2, E2);

    scan1_k<<<nb, 256, 0, stream>>>(rp1, bsum, N);
    scan2_k<<<1, 256, 0, stream>>>(bsum, nb);
    scan3_k<<<gN256, 256, 0, stream>>>(rp1, bsum, N);
    build_k<<<gE1, 256, 0, stream>>>(ei, ei + E, ea, rp1, srcs1, w1, E);

    scan1_k<<<nb, 256, 0, stream>>>(rp2, bsum, N);
    scan2_k<<<1, 256, 0, stream>>>(bsum, nb);
    scan3_k<<<gN256, 256, 0, stream>>>(rp2, bsum, N);
    build_k<<<gE2, 256, 0, stream>>>(ei2, ei2 + E2, ea2, rp2, srcs2, w2, E2);

    // ---- 3 inception blocks ----
    const int gGemm = (N + TM - 1) / TM;
    const int gGather = (N + 7) / 8;

    const float* cur = x;
    for (int b = 0; b < 3; ++b) {
        const float* lnw = (const float*)d_in[5 + 6 * b + 0];
        const float* lnb = (const float*)d_in[5 + 6 * b + 1];
        const float* c1w = (const float*)d_in[5 + 6 * b + 2];
        const float* c1b = (const float*)d_in[5 + 6 * b + 3];
        const float* c2w = (const float*)d_in[5 + 6 * b + 4];
        const float* c2b = (const float*)d_in[5 + 6 * b + 5];

        float* y = (b == 1) ? B : OUT;   // b0 -> OUT, b1 -> ws, b2 -> OUT

        gemm_k<<<gGemm, 256, 0, stream>>>(cur, lnw, lnb, c1b, c2b, y, N);

        gemm_k<<<gGemm, 256, 0, stream>>>(cur, c1w, nullptr, nullptr, nullptr, H, N);
        gather_k<<<gGather, 256, 0, stream>>>(H, srcs1, w1, rp1, y, N);

        gemm_k<<<gGemm, 256, 0, stream>>>(cur, c2w, nullptr, nullptr, nullptr, H, N);
        gather_k<<<gGather, 256, 0, stream>>>(H, srcs2, w2, rp2, y, N);

        cur = y;
    }
}

// Round 3
// 1203.090 us; speedup vs baseline: 13.9947x; 1.5983x over previous
//
#include <hip/hip_runtime.h>
#include <hip/hip_bf16.h>

#define DIM 128
#define NCOL 384

typedef __attribute__((ext_vector_type(8))) short bf16x8;
typedef __attribute__((ext_vector_type(4))) float f32x4;

static __device__ __forceinline__ short f2bf(float f) {
    union { float f; unsigned u; } v; v.f = f;
    unsigned r = (v.u + 0x7FFF + ((v.u >> 16) & 1)) >> 16;   // RN-even
    return (short)r;
}
static __device__ __forceinline__ float asf(unsigned u) {
    union { unsigned u; float f; } v; v.u = u; return v.f;
}

// ------------- weight prep: Wt[mat][n][k] bf16 from W[k][n] fp32 -------------
struct WPtrs { const float* w[9]; };
__global__ __launch_bounds__(256) void prep_w_k(WPtrs p, short* __restrict__ wt)
{
    const int g = blockIdx.x * 256 + threadIdx.x;     // 9 * 16384
    if (g >= 9 * 16384) return;
    const int mat = g >> 14;
    const int i   = g & 16383;
    const int n   = i >> 7, k = i & 127;
    wt[mat * 16384 + n * DIM + k] = f2bf(p.w[mat][k * DIM + n]);
}

// ------------- fused 3-way MFMA GEMM -------------
// Y[:,0:128] = X@lnW + (lnb+c1b+c2b)   (fp32)
// H1 = bf16(X@c1W), H2 = bf16(X@c2W)
// Wt: [384 n][128 k] bf16 (ln | c1 | c2 stacked along n).
// Block: 256 thr = 4 waves; tile 64 rows; each wave owns 16 rows x 384 cols.
__global__ __launch_bounds__(256) void mfma_gemm_k(
    const float* __restrict__ X, const short* __restrict__ Wt,
    const float* __restrict__ b0, const float* __restrict__ b1,
    const float* __restrict__ b2,
    float* __restrict__ Y, short* __restrict__ H1, short* __restrict__ H2,
    int N)
{
    __shared__ __align__(16) short As[64][DIM + 8];   // +8 bf16 pad: no LDS conflicts
    const int t  = threadIdx.x;
    const int m0 = blockIdx.x * 64;

    // stage X tile -> bf16 LDS (float4 coalesced reads)
    for (int idx = t; idx < 64 * 32; idx += 256) {
        const int r  = idx >> 5;
        const int c4 = (idx & 31) << 2;
        float4 v = make_float4(0.f, 0.f, 0.f, 0.f);
        if (m0 + r < N) v = *(const float4*)(X + (size_t)(m0 + r) * DIM + c4);
        short4 s;
        s.x = f2bf(v.x); s.y = f2bf(v.y); s.z = f2bf(v.z); s.w = f2bf(v.w);
        *(short4*)&As[r][c4] = s;
    }
    __syncthreads();

    const int wave  = t >> 6;
    const int lane  = t & 63;
    const int l15   = lane & 15;
    const int kq    = lane >> 4;          // 0..3
    const int mbase = wave * 16;

    // A fragments for the 4 k-steps: A[m=lane&15][k = ks*32 + kq*8 + j]
    bf16x8 afr[4];
#pragma unroll
    for (int ks = 0; ks < 4; ++ks)
        afr[ks] = *(const bf16x8*)&As[mbase + l15][ks * 32 + kq * 8];

    f32x4 acc[24];
#pragma unroll
    for (int ct = 0; ct < 24; ++ct) acc[ct] = (f32x4){0.f, 0.f, 0.f, 0.f};

#pragma unroll
    for (int ks = 0; ks < 4; ++ks) {
        const bf16x8 a = afr[ks];
#pragma unroll
        for (int ct = 0; ct < 24; ++ct) {
            // B[k][n]: lane holds n = ct*16 + (lane&15), k = ks*32 + kq*8 + j
            const bf16x8 b = *(const bf16x8*)(Wt + (ct * 16 + l15) * DIM + ks * 32 + kq * 8);
            acc[ct] = __builtin_amdgcn_mfma_f32_16x16x32_bf16(a, b, acc[ct], 0, 0, 0);
        }
    }

    // epilogue: D col = lane&15, row = (lane>>4)*4 + reg
#pragma unroll
    for (int ct = 0; ct < 24; ++ct) {
        const int col = ct * 16 + l15;
        float bias = 0.f;
        if (col < DIM) bias = b0[col] + b1[col] + b2[col];
#pragma unroll
        for (int r = 0; r < 4; ++r) {
            const int m = m0 + mbase + kq * 4 + r;
            if (m >= N) continue;
            const float v = acc[ct][r];
            if (col < DIM)            Y [(size_t)m * DIM + col]         = v + bias;
            else if (col < 2 * DIM)   H1[(size_t)m * DIM + (col - DIM)]     = f2bf(v);
            else                      H2[(size_t)m * DIM + (col - 2 * DIM)] = f2bf(v);
        }
    }
}

// ---------------- CSR build ----------------
__global__ __launch_bounds__(256) void hist_k(
    const int* __restrict__ dst, int* __restrict__ cnt, int E)
{
    const int e = blockIdx.x * 256 + threadIdx.x;
    if (e < E) atomicAdd(&cnt[dst[e]], 1);
}

#define SCAN_B 1024
__global__ __launch_bounds__(256) void scan1_k(
    int* __restrict__ data, int* __restrict__ bsums, int n)
{
    __shared__ int sh[256];
    const int t = threadIdx.x;
    const int base = blockIdx.x * SCAN_B + t * 4;
    int v[4]; int s = 0;
#pragma unroll
    for (int i = 0; i < 4; ++i) {
        v[i] = (base + i < n) ? data[base + i] : 0;
        s += v[i];
    }
    sh[t] = s;
    __syncthreads();
    for (int off = 1; off < 256; off <<= 1) {
        int x = (t >= off) ? sh[t - off] : 0;
        __syncthreads();
        sh[t] += x;
        __syncthreads();
    }
    int run = (t == 0) ? 0 : sh[t - 1];
#pragma unroll
    for (int i = 0; i < 4; ++i) {
        if (base + i < n) data[base + i] = run;
        run += v[i];
    }
    if (t == 255) bsums[blockIdx.x] = sh[255];
}

__global__ __launch_bounds__(256) void scan2_k(int* __restrict__ bsums, int nb)
{
    __shared__ int sh[256];
    const int t = threadIdx.x;
    sh[t] = (t < nb) ? bsums[t] : 0;
    __syncthreads();
    for (int off = 1; off < 256; off <<= 1) {
        int x = (t >= off) ? sh[t - off] : 0;
        __syncthreads();
        sh[t] += x;
        __syncthreads();
    }
    if (t < nb) bsums[t] = (t == 0) ? 0 : sh[t - 1];
}

__global__ __launch_bounds__(256) void scan3_k(
    int* __restrict__ data, const int* __restrict__ bsums, int n)
{
    const int i = blockIdx.x * 256 + threadIdx.x;
    if (i < n) data[i] += bsums[i / SCAN_B];
}

__global__ __launch_bounds__(256) void build_k(
    const int* __restrict__ src, const int* __restrict__ dst,
    const float* __restrict__ ea, int* __restrict__ off,
    int* __restrict__ srcs, float* __restrict__ wss, int E)
{
    const int e = blockIdx.x * 256 + threadIdx.x;
    if (e >= E) return;
    const int d = dst[e];
    const int pos = atomicAdd(&off[d], 1);
    srcs[pos] = src[e];
    wss[pos]  = ea[e];
}

// ---------------- merged gather: both adjacencies, one y RMW ----------------
static __device__ __forceinline__ void gacc(
    const short* __restrict__ H, const int* __restrict__ srcs,
    const float* __restrict__ wss, int start, int end, int lane, float4& acc)
{
    int j = start;
    for (; j + 3 < end; j += 4) {
        const int   sA = srcs[j],   sB = srcs[j+1], sC = srcs[j+2], sD = srcs[j+3];
        const float wA = wss[j],    wB = wss[j+1],  wC = wss[j+2],  wD = wss[j+3];
        const uint2 hA = *(const uint2*)(H + (size_t)sA * DIM + lane * 4);
        const uint2 hB = *(const uint2*)(H + (size_t)sB * DIM + lane * 4);
        const uint2 hC = *(const uint2*)(H + (size_t)sC * DIM + lane * 4);
        const uint2 hD = *(const uint2*)(H + (size_t)sD * DIM + lane * 4);
        acc.x = fmaf(wA, asf(hA.x << 16), acc.x);
        acc.y = fmaf(wA, asf(hA.x & 0xFFFF0000u), acc.y);
        acc.z = fmaf(wA, asf(hA.y << 16), acc.z);
        acc.w = fmaf(wA, asf(hA.y & 0xFFFF0000u), acc.w);
        acc.x = fmaf(wB, asf(hB.x << 16), acc.x);
        acc.y = fmaf(wB, asf(hB.x & 0xFFFF0000u), acc.y);
        acc.z = fmaf(wB, asf(hB.y << 16), acc.z);
        acc.w = fmaf(wB, asf(hB.y & 0xFFFF0000u), acc.w);
        acc.x = fmaf(wC, asf(hC.x << 16), acc.x);
        acc.y = fmaf(wC, asf(hC.x & 0xFFFF0000u), acc.y);
        acc.z = fmaf(wC, asf(hC.y << 16), acc.z);
        acc.w = fmaf(wC, asf(hC.y & 0xFFFF0000u), acc.w);
        acc.x = fmaf(wD, asf(hD.x << 16), acc.x);
        acc.y = fmaf(wD, asf(hD.x & 0xFFFF0000u), acc.y);
        acc.z = fmaf(wD, asf(hD.y << 16), acc.z);
        acc.w = fmaf(wD, asf(hD.y & 0xFFFF0000u), acc.w);
    }
    for (; j < end; ++j) {
        const int   s = srcs[j];
        const float w = wss[j];
        const uint2 h = *(const uint2*)(H + (size_t)s * DIM + lane * 4);
        acc.x = fmaf(w, asf(h.x << 16), acc.x);
        acc.y = fmaf(w, asf(h.x & 0xFFFF0000u), acc.y);
        acc.z = fmaf(w, asf(h.y << 16), acc.z);
        acc.w = fmaf(w, asf(h.y & 0xFFFF0000u), acc.w);
    }
}

__global__ __launch_bounds__(256) void gather2_k(
    const short* __restrict__ H1, const short* __restrict__ H2,
    const int* __restrict__ s1, const float* __restrict__ w1, const int* __restrict__ o1,
    const int* __restrict__ s2, const float* __restrict__ w2, const int* __restrict__ o2,
    float* __restrict__ Y, int N)
{
    const int node = blockIdx.x * 8 + (threadIdx.x >> 5);
    if (node >= N) return;
    const int lane = threadIdx.x & 31;

    float4 acc = make_float4(0.f, 0.f, 0.f, 0.f);
    gacc(H1, s1, w1, node ? o1[node - 1] : 0, o1[node], lane, acc);
    gacc(H2, s2, w2, node ? o2[node - 1] : 0, o2[node], lane, acc);

    float4* yp = (float4*)(Y + (size_t)node * DIM + lane * 4);
    float4 y = *yp;
    y.x += acc.x; y.y += acc.y; y.z += acc.z; y.w += acc.w;
    *yp = y;
}

extern "C" void kernel_launch(void* const* d_in, const int* in_sizes, int n_in,
                              void* d_out, int out_size, void* d_ws, size_t ws_size,
                              hipStream_t stream)
{
    const float* x   = (const float*)d_in[0];
    const int*   ei  = (const int*)d_in[1];
    const float* ea  = (const float*)d_in[2];
    const int*   ei2 = (const int*)d_in[3];
    const float* ea2 = (const float*)d_in[4];

    const int N  = in_sizes[0] / DIM;
    const int E  = in_sizes[2];
    const int E2 = in_sizes[4];

    float* OUT = (float*)d_out;

    // ---- workspace layout ----
    float* B     = (float*)d_ws;                    // N*DIM f32
    short* H1    = (short*)(B + (size_t)N * DIM);   // N*DIM bf16
    short* H2    = H1 + (size_t)N * DIM;            // N*DIM bf16
    short* WT    = H2 + (size_t)N * DIM;            // 9*16384 bf16
    int*   rp1   = (int*)(WT + 9 * 16384);          // N
    int*   rp2   = rp1 + N;                         // N
    int*   bsum  = rp2 + N;                         // 256
    int*   srcs1 = bsum + 256;                      // E
    float* w1    = (float*)(srcs1 + E);             // E
    int*   srcs2 = (int*)(w1 + E);                  // E2
    float* w2    = (float*)(srcs2 + E2);            // E2

    const int gE1 = (E + 255) / 256;
    const int gE2 = (E2 + 255) / 256;
    const int nb  = (N + SCAN_B - 1) / SCAN_B;
    const int gN256 = (N + 255) / 256;

    // ---- weight prep ----
    WPtrs wp;
    for (int b = 0; b < 3; ++b) {
        wp.w[b * 3 + 0] = (const float*)d_in[5 + 6 * b + 0];  // ln
        wp.w[b * 3 + 1] = (const float*)d_in[5 + 6 * b + 2];  // c1
        wp.w[b * 3 + 2] = (const float*)d_in[5 + 6 * b + 4];  // c2
    }
    prep_w_k<<<(9 * 16384 + 255) / 256, 256, 0, stream>>>(wp, WT);

    // ---- build CSR for both adjacencies ----
    hipMemsetAsync(rp1, 0, 2 * (size_t)N * sizeof(int), stream);
    hist_k<<<gE1, 256, 0, stream>>>(ei + E,   rp1, E);
    hist_k<<<gE2, 256, 0, stream>>>(ei2 + E2, rp2, E2);

    scan1_k<<<nb, 256, 0, stream>>>(rp1, bsum, N);
    scan2_k<<<1, 256, 0, stream>>>(bsum, nb);
    scan3_k<<<gN256, 256, 0, stream>>>(rp1, bsum, N);
    build_k<<<gE1, 256, 0, stream>>>(ei, ei + E, ea, rp1, srcs1, w1, E);

    scan1_k<<<nb, 256, 0, stream>>>(rp2, bsum, N);
    scan2_k<<<1, 256, 0, stream>>>(bsum, nb);
    scan3_k<<<gN256, 256, 0, stream>>>(rp2, bsum, N);
    build_k<<<gE2, 256, 0, stream>>>(ei2, ei2 + E2, ea2, rp2, srcs2, w2, E2);

    // ---- 3 inception blocks ----
    const int gGemm   = (N + 63) / 64;
    const int gGather = (N + 7) / 8;

    const float* cur = x;
    for (int b = 0; b < 3; ++b) {
        const float* lnb = (const float*)d_in[5 + 6 * b + 1];
        const float* c1b = (const float*)d_in[5 + 6 * b + 3];
        const float* c2b = (const float*)d_in[5 + 6 * b + 5];

        float* y = (b == 1) ? B : OUT;   // b0 -> OUT, b1 -> ws, b2 -> OUT

        mfma_gemm_k<<<gGemm, 256, 0, stream>>>(
            cur, WT + (size_t)b * 3 * 16384, lnb, c1b, c2b, y, H1, H2, N);

        gather2_k<<<gGather, 256, 0, stream>>>(
            H1, H2, srcs1, w1, rp1, srcs2, w2, rp2, y, N);

        cur = y;
    }
}

// Round 4
// 1042.796 us; speedup vs baseline: 16.1459x; 1.1537x over previous
//
#include <hip/hip_runtime.h>
#include <hip/hip_bf16.h>

#define DIM 128

typedef __attribute__((ext_vector_type(8))) short bf16x8;
typedef __attribute__((ext_vector_type(4))) float f32x4;

static __device__ __forceinline__ short f2bf(float f) {
    union { float f; unsigned u; } v; v.f = f;
    unsigned r = (v.u + 0x7FFF + ((v.u >> 16) & 1)) >> 16;   // RN-even
    return (short)r;
}
static __device__ __forceinline__ float asf(unsigned u) {
    union { unsigned u; float f; } v; v.u = u; return v.f;
}
static __device__ __forceinline__ unsigned asu(float f) {
    union { float f; unsigned u; } v; v.f = f; return v.u;
}

// ------------- weight prep: pack W[k][n] fp32 -> MFMA-lane-ordered bf16 ------
// Packed layout: frag (mat9, ct8, ks4) at offset ((mat*8+ct)*4+ks)*512,
// lane l holds 8 bf16: n = ct*16 + (l&15), k = ks*32 + (l>>4)*8 + j.
// A wave's B-frag load is then one contiguous 1KB dwordx4 burst.
struct WPtrs { const float* w[9]; };
__global__ __launch_bounds__(256) void prep_w_k(WPtrs p, short* __restrict__ wt)
{
    const int g = blockIdx.x * 256 + threadIdx.x;   // 9*8*4*64 = 18432
    if (g >= 9 * 8 * 4 * 64) return;
    const int lane = g & 63;
    const int ks   = (g >> 6) & 3;
    const int ct   = (g >> 8) & 7;
    const int mat  = g >> 11;
    const int n     = ct * 16 + (lane & 15);
    const int kbase = ks * 32 + (lane >> 4) * 8;
    const float* W = p.w[mat];
    short o[8];
#pragma unroll
    for (int j = 0; j < 8; ++j) o[j] = f2bf(W[(size_t)(kbase + j) * DIM + n]);
    short* dst = wt + (((size_t)(mat * 8 + ct) * 4 + ks) << 9) + lane * 8;
#pragma unroll
    for (int j = 0; j < 8; ++j) dst[j] = o[j];
}

// ------------- fused 3-way MFMA GEMM -------------
// Y = X@lnW + (lnb+c1b+c2b) (fp32);  H1 = bf16(X@c1W);  H2 = bf16(X@c2W)
// Wp: packed per-layer B frags (3 mats * 8 ct * 4 ks * 512).
__global__ __launch_bounds__(256) void mfma_gemm_k(
    const float* __restrict__ X, const short* __restrict__ Wp,
    const float* __restrict__ b0, const float* __restrict__ b1,
    const float* __restrict__ b2,
    float* __restrict__ Y, short* __restrict__ H1, short* __restrict__ H2,
    int N)
{
    __shared__ __align__(16) short As[64][DIM + 8];
    const int t  = threadIdx.x;
    const int m0 = blockIdx.x * 64;

    for (int idx = t; idx < 64 * 32; idx += 256) {
        const int r  = idx >> 5;
        const int c4 = (idx & 31) << 2;
        float4 v = make_float4(0.f, 0.f, 0.f, 0.f);
        if (m0 + r < N) v = *(const float4*)(X + (size_t)(m0 + r) * DIM + c4);
        short4 s;
        s.x = f2bf(v.x); s.y = f2bf(v.y); s.z = f2bf(v.z); s.w = f2bf(v.w);
        *(short4*)&As[r][c4] = s;
    }
    __syncthreads();

    const int wave  = t >> 6;
    const int lane  = t & 63;
    const int l15   = lane & 15;
    const int kq    = lane >> 4;
    const int mbase = wave * 16;

    bf16x8 afr[4];
#pragma unroll
    for (int ks = 0; ks < 4; ++ks)
        afr[ks] = *(const bf16x8*)&As[mbase + l15][ks * 32 + kq * 8];

    f32x4 acc[24];
#pragma unroll
    for (int ct = 0; ct < 24; ++ct) acc[ct] = (f32x4){0.f, 0.f, 0.f, 0.f};

#pragma unroll
    for (int ks = 0; ks < 4; ++ks) {
        const bf16x8 a = afr[ks];
#pragma unroll
        for (int ct = 0; ct < 24; ++ct) {
            const bf16x8 b = *(const bf16x8*)(Wp + (((size_t)ct * 4 + ks) << 9) + lane * 8);
            acc[ct] = __builtin_amdgcn_mfma_f32_16x16x32_bf16(a, b, acc[ct], 0, 0, 0);
        }
    }

    // D: col = ct*16 + (lane&15), row = (lane>>4)*4 + r
#pragma unroll
    for (int ct = 0; ct < 24; ++ct) {
        const int col = ct * 16 + l15;
        float bias = 0.f;
        if (col < DIM) bias = b0[col] + b1[col] + b2[col];
#pragma unroll
        for (int r = 0; r < 4; ++r) {
            const int m = m0 + mbase + kq * 4 + r;
            if (m >= N) continue;
            const float v = acc[ct][r];
            if (col < DIM)            Y [(size_t)m * DIM + col]             = v + bias;
            else if (col < 2 * DIM)   H1[(size_t)m * DIM + (col - DIM)]     = f2bf(v);
            else                      H2[(size_t)m * DIM + (col - 2 * DIM)] = f2bf(v);
        }
    }
}

// ---------------- CSR build (both adjacencies in one 2N array) ----------------
__global__ __launch_bounds__(256) void hist2_k(
    const int* __restrict__ d1, const int* __restrict__ d2,
    int* __restrict__ cnt, int N, int E, int E2)
{
    const int e = blockIdx.x * 256 + threadIdx.x;
    if (e < E)            atomicAdd(&cnt[d1[e]], 1);
    else if (e < E + E2)  atomicAdd(&cnt[N + d2[e - E]], 1);
}

#define SCAN_B 1024
__global__ __launch_bounds__(256) void scan1_k(
    int* __restrict__ data, int* __restrict__ bsums, int n)
{
    __shared__ int sh[256];
    const int t = threadIdx.x;
    const int base = blockIdx.x * SCAN_B + t * 4;
    int v[4]; int s = 0;
#pragma unroll
    for (int i = 0; i < 4; ++i) {
        v[i] = (base + i < n) ? data[base + i] : 0;
        s += v[i];
    }
    sh[t] = s;
    __syncthreads();
    for (int off = 1; off < 256; off <<= 1) {
        int x = (t >= off) ? sh[t - off] : 0;
        __syncthreads();
        sh[t] += x;
        __syncthreads();
    }
    int run = (t == 0) ? 0 : sh[t - 1];
#pragma unroll
    for (int i = 0; i < 4; ++i) {
        if (base + i < n) data[base + i] = run;
        run += v[i];
    }
    if (t == 255) bsums[blockIdx.x] = sh[255];
}

__global__ __launch_bounds__(256) void scan2_k(int* __restrict__ bsums, int nb)
{
    __shared__ int sh[256];
    const int t = threadIdx.x;
    sh[t] = (t < nb) ? bsums[t] : 0;
    __syncthreads();
    for (int off = 1; off < 256; off <<= 1) {
        int x = (t >= off) ? sh[t - off] : 0;
        __syncthreads();
        sh[t] += x;
        __syncthreads();
    }
    if (t < nb) bsums[t] = (t == 0) ? 0 : sh[t - 1];
}

__global__ __launch_bounds__(256) void scan3_k(
    int* __restrict__ data, const int* __restrict__ bsums, int n)
{
    const int i = blockIdx.x * 256 + threadIdx.x;
    if (i < n) data[i] += bsums[i / SCAN_B];
}

// bucket-scatter both adjacencies; pairs[pos] = {src, w-bits} single 8B store.
// Adjacency-1 buckets land in [0,E), adjacency-2 in [E,E+E2) (scan order).
__global__ __launch_bounds__(256) void build2_k(
    const int* __restrict__ s1, const int* __restrict__ d1, const float* __restrict__ ea1,
    const int* __restrict__ s2, const int* __restrict__ d2, const float* __restrict__ ea2,
    int* __restrict__ off, uint2* __restrict__ pairs, int N, int E, int E2)
{
    const int e = blockIdx.x * 256 + threadIdx.x;
    if (e < E) {
        const int pos = atomicAdd(&off[d1[e]], 1);
        pairs[pos] = make_uint2((unsigned)s1[e], asu(ea1[e]));
    } else if (e < E + E2) {
        const int i = e - E;
        const int pos = atomicAdd(&off[N + d2[i]], 1);
        pairs[pos] = make_uint2((unsigned)s2[i], asu(ea2[i]));
    }
}

// ---------------- merged gather ----------------
static __device__ __forceinline__ void bf2acc(unsigned w, uint2 h, float4& acc)
{
    const float wf = asf(w);
    acc.x = fmaf(wf, asf(h.x << 16), acc.x);
    acc.y = fmaf(wf, asf(h.x & 0xFFFF0000u), acc.y);
    acc.z = fmaf(wf, asf(h.y << 16), acc.z);
    acc.w = fmaf(wf, asf(h.y & 0xFFFF0000u), acc.w);
}

static __device__ __forceinline__ void gacc(
    const short* __restrict__ H, const uint2* __restrict__ pairs,
    int start, int end, int lane, float4& acc)
{
    int j = start;
    for (; j + 7 < end; j += 8) {
        uint2 p[8], h[8];
#pragma unroll
        for (int q = 0; q < 8; ++q) p[q] = pairs[j + q];
#pragma unroll
        for (int q = 0; q < 8; ++q)
            h[q] = *(const uint2*)(H + (size_t)p[q].x * DIM + lane * 4);
#pragma unroll
        for (int q = 0; q < 8; ++q) bf2acc(p[q].y, h[q], acc);
    }
    if (j + 3 < end) {
        uint2 p[4], h[4];
#pragma unroll
        for (int q = 0; q < 4; ++q) p[q] = pairs[j + q];
#pragma unroll
        for (int q = 0; q < 4; ++q)
            h[q] = *(const uint2*)(H + (size_t)p[q].x * DIM + lane * 4);
#pragma unroll
        for (int q = 0; q < 4; ++q) bf2acc(p[q].y, h[q], acc);
        j += 4;
    }
    for (; j < end; ++j) {
        const uint2 p = pairs[j];
        const uint2 h = *(const uint2*)(H + (size_t)p.x * DIM + lane * 4);
        bf2acc(p.y, h, acc);
    }
}

__global__ __launch_bounds__(256) void gather2_k(
    const short* __restrict__ H1, const short* __restrict__ H2,
    const uint2* __restrict__ pairs, const int* __restrict__ off,
    float* __restrict__ Y, int N)
{
    const int node = blockIdx.x * 8 + (threadIdx.x >> 5);
    if (node >= N) return;
    const int lane = threadIdx.x & 31;

    const int s1 = node ? off[node - 1] : 0;
    const int e1 = off[node];
    const int s2 = node ? off[N + node - 1] : off[N - 1];
    const int e2 = off[N + node];

    float4 acc = make_float4(0.f, 0.f, 0.f, 0.f);
    gacc(H1, pairs, s1, e1, lane, acc);
    gacc(H2, pairs, s2, e2, lane, acc);

    float4* yp = (float4*)(Y + (size_t)node * DIM + lane * 4);
    float4 y = *yp;
    y.x += acc.x; y.y += acc.y; y.z += acc.z; y.w += acc.w;
    *yp = y;
}

extern "C" void kernel_launch(void* const* d_in, const int* in_sizes, int n_in,
                              void* d_out, int out_size, void* d_ws, size_t ws_size,
                              hipStream_t stream)
{
    const float* x   = (const float*)d_in[0];
    const int*   ei  = (const int*)d_in[1];
    const float* ea  = (const float*)d_in[2];
    const int*   ei2 = (const int*)d_in[3];
    const float* ea2 = (const float*)d_in[4];

    const int N  = in_sizes[0] / DIM;
    const int E  = in_sizes[2];
    const int E2 = in_sizes[4];
    const int ET = E + E2;

    float* OUT = (float*)d_out;

    // ---- workspace layout ----
    float* B     = (float*)d_ws;                     // N*DIM f32
    short* H1    = (short*)(B + (size_t)N * DIM);    // N*DIM bf16
    short* H2    = H1 + (size_t)N * DIM;             // N*DIM bf16
    short* WT    = H2 + (size_t)N * DIM;             // 9*16384 bf16 (packed)
    int*   rp    = (int*)(WT + 9 * 16384);           // 2N combined counts/offsets
    int*   bsum  = rp + 2 * N;                       // 256
    uint2* pairs = (uint2*)(bsum + 256);             // ET * 8B

    const int gET   = (ET + 255) / 256;
    const int nb    = (2 * N + SCAN_B - 1) / SCAN_B;   // must be <=256
    const int gN2   = (2 * N + 255) / 256;

    // ---- weight prep (packed MFMA-lane order) ----
    WPtrs wp;
    for (int b = 0; b < 3; ++b) {
        wp.w[b * 3 + 0] = (const float*)d_in[5 + 6 * b + 0];  // ln
        wp.w[b * 3 + 1] = (const float*)d_in[5 + 6 * b + 2];  // c1
        wp.w[b * 3 + 2] = (const float*)d_in[5 + 6 * b + 4];  // c2
    }
    prep_w_k<<<(18432 + 255) / 256, 256, 0, stream>>>(wp, WT);

    // ---- build combined CSR ----
    hipMemsetAsync(rp, 0, 2 * (size_t)N * sizeof(int), stream);
    hist2_k<<<gET, 256, 0, stream>>>(ei + E, ei2 + E2, rp, N, E, E2);
    scan1_k<<<nb, 256, 0, stream>>>(rp, bsum, 2 * N);
    scan2_k<<<1, 256, 0, stream>>>(bsum, nb);
    scan3_k<<<gN2, 256, 0, stream>>>(rp, bsum, 2 * N);
    build2_k<<<gET, 256, 0, stream>>>(ei, ei + E, ea, ei2, ei2 + E2, ea2,
                                      rp, pairs, N, E, E2);

    // ---- 3 inception blocks ----
    const int gGemm   = (N + 63) / 64;
    const int gGather = (N + 7) / 8;

    const float* cur = x;
    for (int b = 0; b < 3; ++b) {
        const float* lnb = (const float*)d_in[5 + 6 * b + 1];
        const float* c1b = (const float*)d_in[5 + 6 * b + 3];
        const float* c2b = (const float*)d_in[5 + 6 * b + 5];

        float* y = (b == 1) ? B : OUT;   // b0 -> OUT, b1 -> ws, b2 -> OUT

        mfma_gemm_k<<<gGemm, 256, 0, stream>>>(
            cur, WT + (size_t)b * 3 * 16384, lnb, c1b, c2b, y, H1, H2, N);

        gather2_k<<<gGather, 256, 0, stream>>>(H1, H2, pairs, rp, y, N);

        cur = y;
    }
}

// Round 5
// 891.965 us; speedup vs baseline: 18.8761x; 1.1691x over previous
//
#include <hip/hip_runtime.h>
#include <hip/hip_bf16.h>

#define DIM 128
#define CHUNK 8192          // edges per P1 block
#define NBK 256             // padded bucket count (used: ceil(2N/1024) = 196)
#define BSHIFT 10           // bucket covers 1024 virtual dst ids

typedef __attribute__((ext_vector_type(8))) short bf16x8;
typedef __attribute__((ext_vector_type(4))) float f32x4;

static __device__ __forceinline__ short f2bf(float f) {
    union { float f; unsigned u; } v; v.f = f;
    unsigned r = (v.u + 0x7FFF + ((v.u >> 16) & 1)) >> 16;   // RN-even
    return (short)r;
}
static __device__ __forceinline__ float asf(unsigned u) {
    union { unsigned u; float f; } v; v.u = u; return v.f;
}
static __device__ __forceinline__ unsigned asu(float f) {
    union { float f; unsigned u; } v; v.f = f; return v.u;
}

// ------------- weight prep: pack W[k][n] fp32 -> MFMA-lane-ordered bf16 ------
struct WPtrs { const float* w[9]; };
__global__ __launch_bounds__(256) void prep_w_k(WPtrs p, short* __restrict__ wt)
{
    const int g = blockIdx.x * 256 + threadIdx.x;   // 9*8*4*64 = 18432
    if (g >= 9 * 8 * 4 * 64) return;
    const int lane = g & 63;
    const int ks   = (g >> 6) & 3;
    const int ct   = (g >> 8) & 7;
    const int mat  = g >> 11;
    const int n     = ct * 16 + (lane & 15);
    const int kbase = ks * 32 + (lane >> 4) * 8;
    const float* W = p.w[mat];
    short o[8];
#pragma unroll
    for (int j = 0; j < 8; ++j) o[j] = f2bf(W[(size_t)(kbase + j) * DIM + n]);
    short* dst = wt + (((size_t)(mat * 8 + ct) * 4 + ks) << 9) + lane * 8;
#pragma unroll
    for (int j = 0; j < 8; ++j) dst[j] = o[j];
}

// ------------- fused 3-way MFMA GEMM -------------
__global__ __launch_bounds__(256) void mfma_gemm_k(
    const float* __restrict__ X, const short* __restrict__ Wp,
    const float* __restrict__ b0, const float* __restrict__ b1,
    const float* __restrict__ b2,
    float* __restrict__ Y, short* __restrict__ H1, short* __restrict__ H2,
    int N)
{
    __shared__ __align__(16) short As[64][DIM + 8];
    const int t  = threadIdx.x;
    const int m0 = blockIdx.x * 64;

    for (int idx = t; idx < 64 * 32; idx += 256) {
        const int r  = idx >> 5;
        const int c4 = (idx & 31) << 2;
        float4 v = make_float4(0.f, 0.f, 0.f, 0.f);
        if (m0 + r < N) v = *(const float4*)(X + (size_t)(m0 + r) * DIM + c4);
        short4 s;
        s.x = f2bf(v.x); s.y = f2bf(v.y); s.z = f2bf(v.z); s.w = f2bf(v.w);
        *(short4*)&As[r][c4] = s;
    }
    __syncthreads();

    const int wave  = t >> 6;
    const int lane  = t & 63;
    const int l15   = lane & 15;
    const int kq    = lane >> 4;
    const int mbase = wave * 16;

    bf16x8 afr[4];
#pragma unroll
    for (int ks = 0; ks < 4; ++ks)
        afr[ks] = *(const bf16x8*)&As[mbase + l15][ks * 32 + kq * 8];

    f32x4 acc[24];
#pragma unroll
    for (int ct = 0; ct < 24; ++ct) acc[ct] = (f32x4){0.f, 0.f, 0.f, 0.f};

#pragma unroll
    for (int ks = 0; ks < 4; ++ks) {
        const bf16x8 a = afr[ks];
#pragma unroll
        for (int ct = 0; ct < 24; ++ct) {
            const bf16x8 b = *(const bf16x8*)(Wp + (((size_t)ct * 4 + ks) << 9) + lane * 8);
            acc[ct] = __builtin_amdgcn_mfma_f32_16x16x32_bf16(a, b, acc[ct], 0, 0, 0);
        }
    }

#pragma unroll
    for (int ct = 0; ct < 24; ++ct) {
        const int col = ct * 16 + l15;
        float bias = 0.f;
        if (col < DIM) bias = b0[col] + b1[col] + b2[col];
#pragma unroll
        for (int r = 0; r < 4; ++r) {
            const int m = m0 + mbase + kq * 4 + r;
            if (m >= N) continue;
            const float v = acc[ct][r];
            if (col < DIM)            Y [(size_t)m * DIM + col]             = v + bias;
            else if (col < 2 * DIM)   H1[(size_t)m * DIM + (col - DIM)]     = f2bf(v);
            else                      H2[(size_t)m * DIM + (col - 2 * DIM)] = f2bf(v);
        }
    }
}

// =================== binned CSR build ===================
// virtual dst id v in [0, 2N): v = dst (adj1), N + dst (adj2).
// bucket = v >> 10 (196 used); vlow = v & 1023.
// binned elem: x = src | (vlow << 17)   (src < 2^17), y = w bits.

// ---- P0: bucket histogram (LDS-aggregated) ----
__global__ __launch_bounds__(256) void p0_bhist_k(
    const int* __restrict__ d1, const int* __restrict__ d2,
    int* __restrict__ bcnt, int N, int E, int E2)
{
    __shared__ int lh[NBK];
    const int t = threadIdx.x;
    lh[t] = 0;
    __syncthreads();
    const int stride = gridDim.x * 256;
    for (int i = blockIdx.x * 256 + t; i < E;  i += stride) atomicAdd(&lh[d1[i] >> BSHIFT], 1);
    for (int i = blockIdx.x * 256 + t; i < E2; i += stride) atomicAdd(&lh[(N + d2[i]) >> BSHIFT], 1);
    __syncthreads();
    if (lh[t]) atomicAdd(&bcnt[t], lh[t]);
}

// ---- bucket scan (single block): bktbase/cursor = exclusive; rowptr[2N] = ET
__global__ __launch_bounds__(256) void bscan_k(
    const int* __restrict__ bcnt, int* __restrict__ bktbase,
    int* __restrict__ cursor, int* __restrict__ rowptr, int twoN, int ET)
{
    __shared__ int sv[NBK];
    const int t = threadIdx.x;
    sv[t] = bcnt[t];
    __syncthreads();
    for (int off = 1; off < NBK; off <<= 1) {
        int a = (t >= off) ? sv[t - off] : 0;
        __syncthreads();
        sv[t] += a;
        __syncthreads();
    }
    const int excl = t ? sv[t - 1] : 0;
    bktbase[t] = excl;
    cursor[t]  = excl;
    if (t == 0) rowptr[twoN] = ET;
}

// ---- P1: chunk-local LDS counting sort by bucket, coalesced-run flush ----
__global__ __launch_bounds__(256) void p1_bin_k(
    const int* __restrict__ s1, const int* __restrict__ d1, const float* __restrict__ ea1,
    const int* __restrict__ s2, const int* __restrict__ d2, const float* __restrict__ ea2,
    int* __restrict__ cursor, uint2* __restrict__ binned,
    int N, int E, int E2, int nc1)
{
    __shared__ __align__(16) uint2 stage[CHUNK];     // 64 KB
    __shared__ unsigned char lbkt[CHUNK];            // 8 KB
    __shared__ int hist[NBK], exclv[NBK], lcur[NBK], gpos[NBK];

    const int t = threadIdx.x;
    const int c = blockIdx.x;
    const bool a2 = (c >= nc1);
    const int* S  = a2 ? s2  : s1;
    const int* D  = a2 ? d2  : d1;
    const float* W = a2 ? ea2 : ea1;
    const int Eloc = a2 ? E2 : E;
    const int voff = a2 ? N : 0;
    const int eb   = (a2 ? (c - nc1) : c) * CHUNK;
    const int ec   = min(CHUNK, Eloc - eb);

    hist[t] = 0;
    __syncthreads();

    for (int i = t; i < ec; i += 256)
        atomicAdd(&hist[(unsigned)(voff + D[eb + i]) >> BSHIFT], 1);
    __syncthreads();

    // inclusive scan of hist into exclv (then shift)
    exclv[t] = hist[t];
    __syncthreads();
    for (int off = 1; off < NBK; off <<= 1) {
        int a = (t >= off) ? exclv[t - off] : 0;
        __syncthreads();
        exclv[t] += a;
        __syncthreads();
    }
    const int myincl = exclv[t];
    __syncthreads();
    exclv[t] = myincl - hist[t];           // exclusive
    lcur[t]  = exclv[t];
    if (hist[t]) gpos[t] = atomicAdd(&cursor[t], hist[t]);
    __syncthreads();

    // scatter into LDS ordered by bucket
    for (int i = t; i < ec; i += 256) {
        const int v = voff + D[eb + i];
        const int b = (unsigned)v >> BSHIFT;
        const int lpos = atomicAdd(&lcur[b], 1);
        stage[lpos] = make_uint2((unsigned)S[eb + i] | ((unsigned)(v & 1023) << 17),
                                 asu(W[eb + i]));
        lbkt[lpos] = (unsigned char)b;
    }
    __syncthreads();

    // flush: consecutive LDS slots -> per-bucket contiguous global runs
    for (int s = t; s < ec; s += 256) {
        const int b = lbkt[s];
        binned[gpos[b] + (s - exclv[b])] = stage[s];
    }
}

// ---- P2: per-bucket finalize: rowptr + window-local pair scatter ----
__global__ __launch_bounds__(256) void p2_final_k(
    const uint2* __restrict__ binned, const int* __restrict__ bktbase,
    int* __restrict__ rowptr, uint2* __restrict__ pairs, int twoN)
{
    __shared__ int hist[1024], scn[1024], lcur[1024];
    const int t = threadIdx.x;
    const int b = blockIdx.x;
    const int base = bktbase[b];
    const int cnt  = bktbase[b + 1] - base;
    const int vbase = b << BSHIFT;

    for (int i = t; i < 1024; i += 256) hist[i] = 0;
    __syncthreads();

    for (int i = t; i < cnt; i += 256)
        atomicAdd(&hist[binned[base + i].x >> 17], 1);
    __syncthreads();

    // inclusive scan over 1024 with 256 threads (4 per thread)
    for (int i = t; i < 1024; i += 256) scn[i] = hist[i];
    __syncthreads();
    for (int off = 1; off < 1024; off <<= 1) {
        int a0 = (t       >= off) ? scn[t       - off] : 0;
        int a1 = (t + 256 >= off) ? scn[t + 256 - off] : 0;
        int a2 = (t + 512 >= off) ? scn[t + 512 - off] : 0;
        int a3 = (t + 768 >= off) ? scn[t + 768 - off] : 0;
        __syncthreads();
        scn[t] += a0; scn[t + 256] += a1; scn[t + 512] += a2; scn[t + 768] += a3;
        __syncthreads();
    }
    for (int i = t; i < 1024; i += 256) {
        const int excl = scn[i] - hist[i];
        lcur[i] = excl;
        const int v = vbase + i;
        if (v < twoN) rowptr[v] = base + excl;
    }
    __syncthreads();

    for (int i = t; i < cnt; i += 256) {
        const uint2 e = binned[base + i];
        const int vlow = e.x >> 17;
        const int pos = base + atomicAdd(&lcur[vlow], 1);
        pairs[pos] = make_uint2(e.x & 0x1FFFFu, e.y);
    }
}

// ---------------- merged gather ----------------
static __device__ __forceinline__ void bf2acc(unsigned w, uint2 h, float4& acc)
{
    const float wf = asf(w);
    acc.x = fmaf(wf, asf(h.x << 16), acc.x);
    acc.y = fmaf(wf, asf(h.x & 0xFFFF0000u), acc.y);
    acc.z = fmaf(wf, asf(h.y << 16), acc.z);
    acc.w = fmaf(wf, asf(h.y & 0xFFFF0000u), acc.w);
}

static __device__ __forceinline__ void gacc(
    const short* __restrict__ H, const uint2* __restrict__ pairs,
    int start, int end, int lane, float4& acc)
{
    int j = start;
    for (; j + 7 < end; j += 8) {
        uint2 p[8], h[8];
#pragma unroll
        for (int q = 0; q < 8; ++q) p[q] = pairs[j + q];
#pragma unroll
        for (int q = 0; q < 8; ++q)
            h[q] = *(const uint2*)(H + (size_t)p[q].x * DIM + lane * 4);
#pragma unroll
        for (int q = 0; q < 8; ++q) bf2acc(p[q].y, h[q], acc);
    }
    if (j + 3 < end) {
        uint2 p[4], h[4];
#pragma unroll
        for (int q = 0; q < 4; ++q) p[q] = pairs[j + q];
#pragma unroll
        for (int q = 0; q < 4; ++q)
            h[q] = *(const uint2*)(H + (size_t)p[q].x * DIM + lane * 4);
#pragma unroll
        for (int q = 0; q < 4; ++q) bf2acc(p[q].y, h[q], acc);
        j += 4;
    }
    for (; j < end; ++j) {
        const uint2 p = pairs[j];
        const uint2 h = *(const uint2*)(H + (size_t)p.x * DIM + lane * 4);
        bf2acc(p.y, h, acc);
    }
}

__global__ __launch_bounds__(256) void gather2_k(
    const short* __restrict__ H1, const short* __restrict__ H2,
    const uint2* __restrict__ pairs, const int* __restrict__ rowptr,
    float* __restrict__ Y, int N)
{
    const int node = blockIdx.x * 8 + (threadIdx.x >> 5);
    if (node >= N) return;
    const int lane = threadIdx.x & 31;

    const int s1 = rowptr[node];
    const int e1 = rowptr[node + 1];
    const int s2 = rowptr[N + node];
    const int e2 = rowptr[N + node + 1];

    float4 acc = make_float4(0.f, 0.f, 0.f, 0.f);
    gacc(H1, pairs, s1, e1, lane, acc);
    gacc(H2, pairs, s2, e2, lane, acc);

    float4* yp = (float4*)(Y + (size_t)node * DIM + lane * 4);
    float4 y = *yp;
    y.x += acc.x; y.y += acc.y; y.z += acc.z; y.w += acc.w;
    *yp = y;
}

extern "C" void kernel_launch(void* const* d_in, const int* in_sizes, int n_in,
                              void* d_out, int out_size, void* d_ws, size_t ws_size,
                              hipStream_t stream)
{
    const float* x   = (const float*)d_in[0];
    const int*   ei  = (const int*)d_in[1];
    const float* ea  = (const float*)d_in[2];
    const int*   ei2 = (const int*)d_in[3];
    const float* ea2 = (const float*)d_in[4];

    const int N  = in_sizes[0] / DIM;
    const int E  = in_sizes[2];
    const int E2 = in_sizes[4];
    const int ET = E + E2;

    float* OUT = (float*)d_out;

    // ---- workspace layout (~129.4 MB) ----
    float* B      = (float*)d_ws;                    // N*DIM f32; binned aliases here
    short* H1     = (short*)(B + (size_t)N * DIM);   // N*DIM bf16
    short* H2     = H1 + (size_t)N * DIM;            // N*DIM bf16
    short* WT     = H2 + (size_t)N * DIM;            // 9*16384 bf16 (packed)
    int*   rowptr = (int*)(WT + 9 * 16384);          // 2N+1 (padded to 2N+4)
    int*   bcnt   = rowptr + 2 * N + 4;              // NBK
    int*   bktbase= bcnt + NBK;                      // NBK+1 -> pad to NBK+4
    int*   cursor = bktbase + NBK + 4;               // NBK
    uint2* pairs  = (uint2*)(cursor + NBK);          // ET * 8B
    uint2* binned = (uint2*)B;                        // ET * 8B, dead before layer-2 GEMM

    // ---- weight prep ----
    WPtrs wp;
    for (int b = 0; b < 3; ++b) {
        wp.w[b * 3 + 0] = (const float*)d_in[5 + 6 * b + 0];
        wp.w[b * 3 + 1] = (const float*)d_in[5 + 6 * b + 2];
        wp.w[b * 3 + 2] = (const float*)d_in[5 + 6 * b + 4];
    }
    prep_w_k<<<(18432 + 255) / 256, 256, 0, stream>>>(wp, WT);

    // ---- binned CSR build ----
    const int nc1 = (E + CHUNK - 1) / CHUNK;
    const int nc2 = (E2 + CHUNK - 1) / CHUNK;
    const int nbk_used = (2 * N + (1 << BSHIFT) - 1) >> BSHIFT;   // must be <= NBK

    hipMemsetAsync(bcnt, 0, NBK * sizeof(int), stream);
    p0_bhist_k<<<256, 256, 0, stream>>>(ei + E, ei2 + E2, bcnt, N, E, E2);
    bscan_k<<<1, NBK, 0, stream>>>(bcnt, bktbase, cursor, rowptr, 2 * N, ET);
    p1_bin_k<<<nc1 + nc2, 256, 0, stream>>>(ei, ei + E, ea, ei2, ei2 + E2, ea2,
                                            cursor, binned, N, E, E2, nc1);
    p2_final_k<<<nbk_used, 256, 0, stream>>>(binned, bktbase, rowptr, pairs, 2 * N);

    // ---- 3 inception blocks ----
    const int gGemm   = (N + 63) / 64;
    const int gGather = (N + 7) / 8;

    const float* cur = x;
    for (int b = 0; b < 3; ++b) {
        const float* lnb = (const float*)d_in[5 + 6 * b + 1];
        const float* c1b = (const float*)d_in[5 + 6 * b + 3];
        const float* c2b = (const float*)d_in[5 + 6 * b + 5];

        float* y = (b == 1) ? B : OUT;   // b0 -> OUT, b1 -> ws, b2 -> OUT

        mfma_gemm_k<<<gGemm, 256, 0, stream>>>(
            cur, WT + (size_t)b * 3 * 16384, lnb, c1b, c2b, y, H1, H2, N);

        gather2_k<<<gGather, 256, 0, stream>>>(H1, H2, pairs, rowptr, y, N);

        cur = y;
    }
}

// Round 6
// 869.026 us; speedup vs baseline: 19.3744x; 1.0264x over previous
//
#include <hip/hip_runtime.h>
#include <hip/hip_bf16.h>

#define DIM 128
#define CHUNK 8192          // edges per P1 block
#define NBK 256             // padded bucket count (used: ceil(2N/1024) = 196)
#define BSHIFT 10           // bucket covers 1024 virtual dst ids

typedef __attribute__((ext_vector_type(8))) short bf16x8;
typedef __attribute__((ext_vector_type(4))) float f32x4;
typedef __attribute__((ext_vector_type(2))) unsigned u32x2;

static __device__ __forceinline__ short f2bf(float f) {
    union { float f; unsigned u; } v; v.f = f;
    unsigned r = (v.u + 0x7FFF + ((v.u >> 16) & 1)) >> 16;   // RN-even
    return (short)r;
}
static __device__ __forceinline__ float asf(unsigned u) {
    union { unsigned u; float f; } v; v.u = u; return v.f;
}
static __device__ __forceinline__ unsigned asu(float f) {
    union { float f; unsigned u; } v; v.f = f; return v.u;
}

// ------------- weight prep: pack W[k][n] fp32 -> (layer, ks, ct) bf16 --------
// Per layer (3 mats): frag (ks4, ct24) at layer*49152 + (ks*24 + ct)*512,
// lane l holds 8 bf16: n = ctl*16 + (l&15), k = ks*32 + (l>>4)*8 + j,
// where ct = mat_local*8 + ctl. One ks-chunk = contiguous 24 KB.
struct WPtrs { const float* w[9]; };
__global__ __launch_bounds__(256) void prep_w_k(WPtrs p, short* __restrict__ wt)
{
    const int g = blockIdx.x * 256 + threadIdx.x;   // 9*8*4*64 = 18432
    if (g >= 9 * 8 * 4 * 64) return;
    const int lane = g & 63;
    const int ks   = (g >> 6) & 3;
    const int ctl  = (g >> 8) & 7;
    const int mat  = g >> 11;
    const int layer = mat / 3;
    const int matl  = mat % 3;
    const int n     = ctl * 16 + (lane & 15);
    const int kbase = ks * 32 + (lane >> 4) * 8;
    const float* W = p.w[mat];
    short o[8];
#pragma unroll
    for (int j = 0; j < 8; ++j) o[j] = f2bf(W[(size_t)(kbase + j) * DIM + n]);
    short* dst = wt + (size_t)layer * 49152
                    + ((size_t)(ks * 24 + matl * 8 + ctl) << 9) + lane * 8;
#pragma unroll
    for (int j = 0; j < 8; ++j) dst[j] = o[j];
}

// ------------- fused 3-way MFMA GEMM (B staged through LDS per ks) ----------
// Y = X@lnW + (lnb+c1b+c2b) (fp32);  H1 = bf16(X@c1W);  H2 = bf16(X@c2W)
__global__ __launch_bounds__(256) void mfma_gemm_k(
    const float* __restrict__ X, const short* __restrict__ Wp,
    const float* __restrict__ b0, const float* __restrict__ b1,
    const float* __restrict__ b2,
    float* __restrict__ Y, short* __restrict__ H1, short* __restrict__ H2,
    int N)
{
    __shared__ __align__(16) short As[64][DIM + 8];   // 17.4 KB
    __shared__ __align__(16) short Bs[24 * 512];      // 24 KB ks-chunk
    const int t  = threadIdx.x;
    const int m0 = blockIdx.x * 64;

    for (int idx = t; idx < 64 * 32; idx += 256) {
        const int r  = idx >> 5;
        const int c4 = (idx & 31) << 2;
        float4 v = make_float4(0.f, 0.f, 0.f, 0.f);
        if (m0 + r < N) v = *(const float4*)(X + (size_t)(m0 + r) * DIM + c4);
        short4 s;
        s.x = f2bf(v.x); s.y = f2bf(v.y); s.z = f2bf(v.z); s.w = f2bf(v.w);
        *(short4*)&As[r][c4] = s;
    }
    __syncthreads();

    const int wave  = t >> 6;
    const int lane  = t & 63;
    const int l15   = lane & 15;
    const int kq    = lane >> 4;
    const int mbase = wave * 16;

    bf16x8 afr[4];
#pragma unroll
    for (int ks = 0; ks < 4; ++ks)
        afr[ks] = *(const bf16x8*)&As[mbase + l15][ks * 32 + kq * 8];

    f32x4 acc[24];
#pragma unroll
    for (int ct = 0; ct < 24; ++ct) acc[ct] = (f32x4){0.f, 0.f, 0.f, 0.f};

    for (int ks = 0; ks < 4; ++ks) {
        if (ks) __syncthreads();                     // all waves done with Bs
        const uint4* wsrc = (const uint4*)(Wp + ks * 12288);
#pragma unroll
        for (int i = 0; i < 6; ++i)
            ((uint4*)Bs)[t + i * 256] = wsrc[t + i * 256];
        __syncthreads();

        const bf16x8 a = afr[ks];
#pragma unroll
        for (int ct = 0; ct < 24; ++ct) {
            const bf16x8 b = *(const bf16x8*)&Bs[ct * 512 + lane * 8];
            acc[ct] = __builtin_amdgcn_mfma_f32_16x16x32_bf16(a, b, acc[ct], 0, 0, 0);
        }
    }

    // D: col = ct*16 + (lane&15), row = (lane>>4)*4 + r
#pragma unroll
    for (int ct = 0; ct < 24; ++ct) {
        const int col = ct * 16 + l15;
        float bias = 0.f;
        if (col < DIM) bias = b0[col] + b1[col] + b2[col];
#pragma unroll
        for (int r = 0; r < 4; ++r) {
            const int m = m0 + mbase + kq * 4 + r;
            if (m >= N) continue;
            const float v = acc[ct][r];
            if (col < DIM)            Y [(size_t)m * DIM + col]             = v + bias;
            else if (col < 2 * DIM)   H1[(size_t)m * DIM + (col - DIM)]     = f2bf(v);
            else                      H2[(size_t)m * DIM + (col - 2 * DIM)] = f2bf(v);
        }
    }
}

// =================== binned CSR build ===================
// virtual dst id v in [0, 2N): v = dst (adj1), N + dst (adj2).
// bucket = v >> 10 (196 used); vlow = v & 1023.
// binned elem: x = src | (vlow << 17)   (src < 2^17), y = w bits.

__global__ __launch_bounds__(256) void p0_bhist_k(
    const int* __restrict__ d1, const int* __restrict__ d2,
    int* __restrict__ bcnt, int N, int E, int E2)
{
    __shared__ int lh[NBK];
    const int t = threadIdx.x;
    lh[t] = 0;
    __syncthreads();
    const int stride = gridDim.x * 256;
    for (int i = blockIdx.x * 256 + t; i < E;  i += stride) atomicAdd(&lh[d1[i] >> BSHIFT], 1);
    for (int i = blockIdx.x * 256 + t; i < E2; i += stride) atomicAdd(&lh[(N + d2[i]) >> BSHIFT], 1);
    __syncthreads();
    if (lh[t]) atomicAdd(&bcnt[t], lh[t]);
}

__global__ __launch_bounds__(256) void bscan_k(
    const int* __restrict__ bcnt, int* __restrict__ bktbase,
    int* __restrict__ cursor, int* __restrict__ rowptr, int twoN, int ET)
{
    __shared__ int sv[NBK];
    const int t = threadIdx.x;
    sv[t] = bcnt[t];
    __syncthreads();
    for (int off = 1; off < NBK; off <<= 1) {
        int a = (t >= off) ? sv[t - off] : 0;
        __syncthreads();
        sv[t] += a;
        __syncthreads();
    }
    const int excl = t ? sv[t - 1] : 0;
    bktbase[t] = excl;
    cursor[t]  = excl;
    if (t == 0) rowptr[twoN] = ET;
}

__global__ __launch_bounds__(256) void p1_bin_k(
    const int* __restrict__ s1, const int* __restrict__ d1, const float* __restrict__ ea1,
    const int* __restrict__ s2, const int* __restrict__ d2, const float* __restrict__ ea2,
    int* __restrict__ cursor, uint2* __restrict__ binned,
    int N, int E, int E2, int nc1)
{
    __shared__ __align__(16) uint2 stage[CHUNK];     // 64 KB
    __shared__ unsigned char lbkt[CHUNK];            // 8 KB
    __shared__ int hist[NBK], exclv[NBK], lcur[NBK], gpos[NBK];

    const int t = threadIdx.x;
    const int c = blockIdx.x;
    const bool a2 = (c >= nc1);
    const int* S  = a2 ? s2  : s1;
    const int* D  = a2 ? d2  : d1;
    const float* W = a2 ? ea2 : ea1;
    const int Eloc = a2 ? E2 : E;
    const int voff = a2 ? N : 0;
    const int eb   = (a2 ? (c - nc1) : c) * CHUNK;
    const int ec   = min(CHUNK, Eloc - eb);

    hist[t] = 0;
    __syncthreads();

    for (int i = t; i < ec; i += 256)
        atomicAdd(&hist[(unsigned)(voff + D[eb + i]) >> BSHIFT], 1);
    __syncthreads();

    exclv[t] = hist[t];
    __syncthreads();
    for (int off = 1; off < NBK; off <<= 1) {
        int a = (t >= off) ? exclv[t - off] : 0;
        __syncthreads();
        exclv[t] += a;
        __syncthreads();
    }
    const int myincl = exclv[t];
    __syncthreads();
    exclv[t] = myincl - hist[t];
    lcur[t]  = exclv[t];
    if (hist[t]) gpos[t] = atomicAdd(&cursor[t], hist[t]);
    __syncthreads();

    for (int i = t; i < ec; i += 256) {
        const int v = voff + D[eb + i];
        const int b = (unsigned)v >> BSHIFT;
        const int lpos = atomicAdd(&lcur[b], 1);
        stage[lpos] = make_uint2((unsigned)S[eb + i] | ((unsigned)(v & 1023) << 17),
                                 asu(W[eb + i]));
        lbkt[lpos] = (unsigned char)b;
    }
    __syncthreads();

    for (int s = t; s < ec; s += 256) {
        const int b = lbkt[s];
        binned[gpos[b] + (s - exclv[b])] = stage[s];
    }
}

__global__ __launch_bounds__(256) void p2_final_k(
    const uint2* __restrict__ binned, const int* __restrict__ bktbase,
    int* __restrict__ rowptr, uint2* __restrict__ pairs, int twoN)
{
    __shared__ int hist[1024], scn[1024], lcur[1024];
    const int t = threadIdx.x;
    const int b = blockIdx.x;
    const int base = bktbase[b];
    const int cnt  = bktbase[b + 1] - base;
    const int vbase = b << BSHIFT;

    for (int i = t; i < 1024; i += 256) hist[i] = 0;
    __syncthreads();

    for (int i = t; i < cnt; i += 256)
        atomicAdd(&hist[binned[base + i].x >> 17], 1);
    __syncthreads();

    for (int i = t; i < 1024; i += 256) scn[i] = hist[i];
    __syncthreads();
    for (int off = 1; off < 1024; off <<= 1) {
        int a0 = (t       >= off) ? scn[t       - off] : 0;
        int a1 = (t + 256 >= off) ? scn[t + 256 - off] : 0;
        int a2 = (t + 512 >= off) ? scn[t + 512 - off] : 0;
        int a3 = (t + 768 >= off) ? scn[t + 768 - off] : 0;
        __syncthreads();
        scn[t] += a0; scn[t + 256] += a1; scn[t + 512] += a2; scn[t + 768] += a3;
        __syncthreads();
    }
    for (int i = t; i < 1024; i += 256) {
        const int excl = scn[i] - hist[i];
        lcur[i] = excl;
        const int v = vbase + i;
        if (v < twoN) rowptr[v] = base + excl;
    }
    __syncthreads();

    for (int i = t; i < cnt; i += 256) {
        const uint2 e = binned[base + i];
        const int vlow = e.x >> 17;
        const int pos = base + atomicAdd(&lcur[vlow], 1);
        pairs[pos] = make_uint2(e.x & 0x1FFFFu, e.y);
    }
}

// ---------------- merged gather (nt on pairs + Y) ----------------
static __device__ __forceinline__ void bf2acc(unsigned w, uint2 h, f32x4& acc)
{
    const float wf = asf(w);
    acc.x = fmaf(wf, asf(h.x << 16), acc.x);
    acc.y = fmaf(wf, asf(h.x & 0xFFFF0000u), acc.y);
    acc.z = fmaf(wf, asf(h.y << 16), acc.z);
    acc.w = fmaf(wf, asf(h.y & 0xFFFF0000u), acc.w);
}

static __device__ __forceinline__ void gacc(
    const short* __restrict__ H, const uint2* __restrict__ pairs,
    int start, int end, int lane, f32x4& acc)
{
    int j = start;
    for (; j + 7 < end; j += 8) {
        u32x2 p[8]; uint2 h[8];
#pragma unroll
        for (int q = 0; q < 8; ++q)
            p[q] = __builtin_nontemporal_load((const u32x2*)(pairs + j + q));
#pragma unroll
        for (int q = 0; q < 8; ++q)
            h[q] = *(const uint2*)(H + (size_t)p[q].x * DIM + lane * 4);
#pragma unroll
        for (int q = 0; q < 8; ++q) bf2acc(p[q].y, h[q], acc);
    }
    if (j + 3 < end) {
        u32x2 p[4]; uint2 h[4];
#pragma unroll
        for (int q = 0; q < 4; ++q)
            p[q] = __builtin_nontemporal_load((const u32x2*)(pairs + j + q));
#pragma unroll
        for (int q = 0; q < 4; ++q)
            h[q] = *(const uint2*)(H + (size_t)p[q].x * DIM + lane * 4);
#pragma unroll
        for (int q = 0; q < 4; ++q) bf2acc(p[q].y, h[q], acc);
        j += 4;
    }
    for (; j < end; ++j) {
        const u32x2 p = __builtin_nontemporal_load((const u32x2*)(pairs + j));
        const uint2 h = *(const uint2*)(H + (size_t)p.x * DIM + lane * 4);
        bf2acc(p.y, h, acc);
    }
}

__global__ __launch_bounds__(256) void gather2_k(
    const short* __restrict__ H1, const short* __restrict__ H2,
    const uint2* __restrict__ pairs, const int* __restrict__ rowptr,
    float* __restrict__ Y, int N)
{
    const int node = blockIdx.x * 8 + (threadIdx.x >> 5);
    if (node >= N) return;
    const int lane = threadIdx.x & 31;

    const int s1 = rowptr[node];
    const int e1 = rowptr[node + 1];
    const int s2 = rowptr[N + node];
    const int e2 = rowptr[N + node + 1];

    f32x4 acc = (f32x4){0.f, 0.f, 0.f, 0.f};
    gacc(H1, pairs, s1, e1, lane, acc);
    gacc(H2, pairs, s2, e2, lane, acc);

    f32x4* yp = (f32x4*)(Y + (size_t)node * DIM + lane * 4);
    f32x4 y = __builtin_nontemporal_load(yp);
    y += acc;
    __builtin_nontemporal_store(y, yp);
}

extern "C" void kernel_launch(void* const* d_in, const int* in_sizes, int n_in,
                              void* d_out, int out_size, void* d_ws, size_t ws_size,
                              hipStream_t stream)
{
    const float* x   = (const float*)d_in[0];
    const int*   ei  = (const int*)d_in[1];
    const float* ea  = (const float*)d_in[2];
    const int*   ei2 = (const int*)d_in[3];
    const float* ea2 = (const float*)d_in[4];

    const int N  = in_sizes[0] / DIM;
    const int E  = in_sizes[2];
    const int E2 = in_sizes[4];
    const int ET = E + E2;

    float* OUT = (float*)d_out;

    // ---- workspace layout (~129.4 MB) ----
    float* B      = (float*)d_ws;                    // N*DIM f32; binned aliases here
    short* H1     = (short*)(B + (size_t)N * DIM);   // N*DIM bf16
    short* H2     = H1 + (size_t)N * DIM;            // N*DIM bf16
    short* WT     = H2 + (size_t)N * DIM;            // 9*16384 bf16 (packed)
    int*   rowptr = (int*)(WT + 9 * 16384);          // 2N+1 (padded to 2N+4)
    int*   bcnt   = rowptr + 2 * N + 4;              // NBK
    int*   bktbase= bcnt + NBK;                      // NBK+1 -> pad to NBK+4
    int*   cursor = bktbase + NBK + 4;               // NBK
    uint2* pairs  = (uint2*)(cursor + NBK);          // ET * 8B
    uint2* binned = (uint2*)B;                        // ET * 8B, dead before layer-2 GEMM

    // ---- weight prep ----
    WPtrs wp;
    for (int b = 0; b < 3; ++b) {
        wp.w[b * 3 + 0] = (const float*)d_in[5 + 6 * b + 0];
        wp.w[b * 3 + 1] = (const float*)d_in[5 + 6 * b + 2];
        wp.w[b * 3 + 2] = (const float*)d_in[5 + 6 * b + 4];
    }
    prep_w_k<<<(18432 + 255) / 256, 256, 0, stream>>>(wp, WT);

    // ---- binned CSR build ----
    const int nc1 = (E + CHUNK - 1) / CHUNK;
    const int nc2 = (E2 + CHUNK - 1) / CHUNK;
    const int nbk_used = (2 * N + (1 << BSHIFT) - 1) >> BSHIFT;   // <= NBK

    hipMemsetAsync(bcnt, 0, NBK * sizeof(int), stream);
    p0_bhist_k<<<256, 256, 0, stream>>>(ei + E, ei2 + E2, bcnt, N, E, E2);
    bscan_k<<<1, NBK, 0, stream>>>(bcnt, bktbase, cursor, rowptr, 2 * N, ET);
    p1_bin_k<<<nc1 + nc2, 256, 0, stream>>>(ei, ei + E, ea, ei2, ei2 + E2, ea2,
                                            cursor, binned, N, E, E2, nc1);
    p2_final_k<<<nbk_used, 256, 0, stream>>>(binned, bktbase, rowptr, pairs, 2 * N);

    // ---- 3 inception blocks ----
    const int gGemm   = (N + 63) / 64;
    const int gGather = (N + 7) / 8;

    const float* cur = x;
    for (int b = 0; b < 3; ++b) {
        const float* lnb = (const float*)d_in[5 + 6 * b + 1];
        const float* c1b = (const float*)d_in[5 + 6 * b + 3];
        const float* c2b = (const float*)d_in[5 + 6 * b + 5];

        float* y = (b == 1) ? B : OUT;   // b0 -> OUT, b1 -> ws, b2 -> OUT

        mfma_gemm_k<<<gGemm, 256, 0, stream>>>(
            cur, WT + (size_t)b * 49152, lnb, c1b, c2b, y, H1, H2, N);

        gather2_k<<<gGather, 256, 0, stream>>>(H1, H2, pairs, rowptr, y, N);

        cur = y;
    }
}